// Round 4
// baseline (628.466 us; speedup 1.0000x reference)
//
#include <hip/hip_runtime.h>
#include <math.h>

// ---------------------------------------------------------------------------
// GriffinRecurrentBlock. R4: GEMM = 256x256 8-wave, BK=64, 4 phases/K-tile,
// COUNTED vmcnt(10) pipeline (T4): LDS split into 8 independent 16KB units
// ({A,B} x {kh0,kh1} x 2 slots); exactly one unit (2 global_load_lds) staged
// per phase, issue->wait distance 6-7 phases, waits never drain to 0 except
// the peeled last tiles. Unit layout [256 rows][32 halfs], 16B-block XOR
// swizzle j^=( (row>>1)&3 ) (2-way bank aliasing = free), source-pre-permuted.
// ---------------------------------------------------------------------------

#define B_ 8
#define T_ 4096
#define H_ 1024
#define M_ (B_ * T_)          // 32768
#define NC_ 128               // chunks per sequence
#define CL_ 32                // chunk length (T_/NC_)

typedef _Float16 half8 __attribute__((ext_vector_type(8)));
typedef _Float16 half4 __attribute__((ext_vector_type(4)));
typedef float    f32x4 __attribute__((ext_vector_type(4)));

#define FENCE asm volatile("" ::: "memory")
#define BAR() do { FENCE; __builtin_amdgcn_s_barrier(); FENCE; } while (0)
#define MFMA16(a, b, c) __builtin_amdgcn_mfma_f32_16x16x32_f16((a), (b), (c), 0, 0, 0)
#define VM10 asm volatile("s_waitcnt vmcnt(10)" ::: "memory")
#define VM8  asm volatile("s_waitcnt vmcnt(8)"  ::: "memory")
#define VM4  asm volatile("s_waitcnt vmcnt(4)"  ::: "memory")
#define VM0  asm volatile("s_waitcnt vmcnt(0)"  ::: "memory")

__device__ __forceinline__ void load16_lds(const _Float16* g, _Float16* l) {
  __builtin_amdgcn_global_load_lds(
      (const __attribute__((address_space(1))) void*)g,
      (__attribute__((address_space(3))) void*)l, 16, 0, 0);
}

// ---------------- prep: 32x32 LDS transpose + fp32->fp16 -------------------
__global__ __launch_bounds__(256) void transpose_cvt(
    const float* __restrict__ sA, const float* __restrict__ sB,
    _Float16* __restrict__ dst) {
  __shared__ float tile[32][33];
  int bn = blockIdx.x * 32;
  int bk = blockIdx.y * 32;
  const float* src = (bn < 1024) ? sA : sB;
  int nof = (bn < 1024) ? bn : bn - 1024;
  int c  = threadIdx.x & 31;
  int r0 = threadIdx.x >> 5;
#pragma unroll
  for (int i = 0; i < 4; ++i) {
    int r = r0 + i * 8;
    tile[r][c] = src[(size_t)(bk + r) * 1024 + nof + c];
  }
  __syncthreads();
#pragma unroll
  for (int i = 0; i < 4; ++i) {
    int nl = r0 + i * 8;
    dst[(size_t)(bn + nl) * 1024 + bk + c] = (_Float16)tile[c][nl];
  }
}

__global__ void prep_bias(const float* __restrict__ bx, const float* __restrict__ by,
                          const float* __restrict__ gib, const float* __restrict__ gab,
                          float* __restrict__ b1, float* __restrict__ b2) {
  int i = blockIdx.x * 1024 + threadIdx.x;   // 0..4095
  if (i < 1024)      b1[i] = bx[i];
  else if (i < 2048) b1[i] = by[i - 1024];
  else if (i < 3072) b2[i - 2048] = gib[i - 2048];
  else               b2[i - 2048] = gab[i - 3072];
}

__global__ __launch_bounds__(256) void cvt_fp16(
    const float* __restrict__ x, _Float16* __restrict__ xh, long n4) {
  for (long i = (long)blockIdx.x * 256 + threadIdx.x; i < n4;
       i += (long)gridDim.x * 256) {
    f32x4 v = ((const f32x4*)x)[i];
    half4 h;
#pragma unroll
    for (int e = 0; e < 4; ++e) h[e] = (_Float16)v[e];
    ((half4*)xh)[i] = h;
  }
}

// ---------------- GEMM: C[M][2048] = A[M][1024] * Bt[2048][1024]^T ----------
// 256x256 tile, 8 waves (2m x 4n), per-wave 128x64, BK=64, 16 K-tiles.
// LDS units: A[slot][kh], B[slot][kh] (slot = kt&1), each 256 rows x 32 halfs.
// Per K-tile phases (16 MFMA each):
//   p0: read A(kh0,mi0-3)+B(kh0,nj0-3); stage A(t+1,k1); MFMA
//   p1: read A(kh0,mi4-7);              stage B(t+2,k0); MFMA; vmcnt(10)
//   p2: read A(kh1,mi0-3)+B(kh1,nj0-3); stage A(t+2,k0); MFMA
//   p3: read A(kh1,mi4-7);              stage B(t+2,k1); MFMA; vmcnt(10)
// Stage of each unit lands exactly 1 phase after its slot's last read.
template <int MODE>
__global__ __launch_bounds__(512, 2) void gemm_kernel(
    const _Float16* __restrict__ A, const _Float16* __restrict__ Bt,
    const float* __restrict__ bias, const float* __restrict__ a_param,
    _Float16* __restrict__ C) {
  __shared__ _Float16 ldsA[32768];   // 64 KB: [slot][kh] 4 units of 8192
  __shared__ _Float16 ldsB[32768];   // 64 KB
  int tid  = threadIdx.x;
  int lane = tid & 63;
  int wave = tid >> 6;
  int l15 = lane & 15, g = lane >> 4;

  // XCD-bijective swizzle (grid = 1024 = 8*128)
  int nb = ((int)blockIdx.x & 7) * 128 + ((int)blockIdx.x >> 3);
  int m0 = (nb >> 3) * 256;           // 128 m-tiles
  int n0 = (nb & 7) * 256;            // 8 n-tiles
  int wm = wave >> 2;                 // 0..1
  int wn = wave & 3;                  // 0..3

  // --- staging: thread -> row (tid>>2), phys 16B-block (tid&3);
  //     global block = phys ^ f(row), f(row) = (row>>1)&3 = (tid>>3)&3.
  int gsrc = (tid & 3) ^ ((tid >> 3) & 3);
  const _Float16* pA = A  + (size_t)(m0 + (tid >> 2)) * 1024 + gsrc * 8;
  const _Float16* pB = Bt + (size_t)(n0 + (tid >> 2)) * 1024 + gsrc * 8;
  _Float16* stA = ldsA + wave * 512;  // HW adds lane*16B
  _Float16* stB = ldsB + wave * 512;

#define STAGE_A(kt, kh)                                                       \
  do {                                                                        \
    const _Float16* s_ = pA + (kt) * 64 + (kh) * 32;                          \
    _Float16* d_ = stA + (((kt) & 1) * 2 + (kh)) * 8192;                      \
    load16_lds(s_, d_);                    /* rows   0..127 */                \
    load16_lds(s_ + 131072, d_ + 4096);    /* rows 128..255 */                \
  } while (0)
#define STAGE_B(kt, kh)                                                       \
  do {                                                                        \
    const _Float16* s_ = pB + (kt) * 64 + (kh) * 32;                          \
    _Float16* d_ = stB + (((kt) & 1) * 2 + (kh)) * 8192;                      \
    load16_lds(s_, d_);                                                       \
    load16_lds(s_ + 131072, d_ + 4096);                                       \
  } while (0)

  // --- fragment read offsets (halfs): row r at r*32, block j = g ^ f(r),
  //     f(r) = (r>>1)&3 = (l15>>1)&3 (mi/nj/wm multiples of 4 rows drop out).
  int jj8  = ((g ^ ((l15 >> 1) & 3)) << 3);
  int aoff = wm * 4096 + l15 * 32 + jj8;   // + slot*16384 + kh*8192 + mi*512
  int boff = wn * 2048 + l15 * 32 + jj8;   // + slot*16384 + kh*8192 + nj*512

  f32x4 acc[8][4];
#pragma unroll
  for (int i = 0; i < 8; ++i)
#pragma unroll
    for (int j = 0; j < 4; ++j) acc[i][j] = (f32x4){0.f, 0.f, 0.f, 0.f};

  half8 a0[4], a1[4], b[4];

#define KTILE(SL, ST0, ST1, ST2, ST3, W1, W2)                                 \
  do {                                                                        \
    const int pl = (SL) * 16384;                                              \
    /* ---- p0: kh0, mi 0-3 ---- */                                           \
    _Pragma("unroll") for (int q = 0; q < 4; ++q)                             \
      a0[q] = *(const half8*)(ldsA + pl + q * 512 + aoff);                    \
    _Pragma("unroll") for (int q = 0; q < 4; ++q)                             \
      b[q]  = *(const half8*)(ldsB + pl + q * 512 + boff);                    \
    ST0;                                                                      \
    BAR();                                                                    \
    __builtin_amdgcn_s_setprio(1);                                            \
    _Pragma("unroll") for (int q = 0; q < 4; ++q) {                           \
      acc[q][0] = MFMA16(a0[q], b[0], acc[q][0]);                             \
      acc[q][1] = MFMA16(a0[q], b[1], acc[q][1]);                             \
      acc[q][2] = MFMA16(a0[q], b[2], acc[q][2]);                             \
      acc[q][3] = MFMA16(a0[q], b[3], acc[q][3]);                             \
    }                                                                         \
    __builtin_amdgcn_s_setprio(0);                                            \
    BAR();                                                                    \
    /* ---- p1: kh0, mi 4-7 ---- */                                           \
    _Pragma("unroll") for (int q = 0; q < 4; ++q)                             \
      a1[q] = *(const half8*)(ldsA + pl + 2048 + q * 512 + aoff);             \
    ST1;                                                                      \
    BAR();                                                                    \
    __builtin_amdgcn_s_setprio(1);                                            \
    _Pragma("unroll") for (int q = 0; q < 4; ++q) {                           \
      acc[4 + q][0] = MFMA16(a1[q], b[0], acc[4 + q][0]);                     \
      acc[4 + q][1] = MFMA16(a1[q], b[1], acc[4 + q][1]);                     \
      acc[4 + q][2] = MFMA16(a1[q], b[2], acc[4 + q][2]);                     \
      acc[4 + q][3] = MFMA16(a1[q], b[3], acc[4 + q][3]);                     \
    }                                                                         \
    __builtin_amdgcn_s_setprio(0);                                            \
    W1;                                                                       \
    BAR();                                                                    \
    /* ---- p2: kh1, mi 0-3 ---- */                                           \
    _Pragma("unroll") for (int q = 0; q < 4; ++q)                             \
      a0[q] = *(const half8*)(ldsA + pl + 8192 + q * 512 + aoff);             \
    _Pragma("unroll") for (int q = 0; q < 4; ++q)                             \
      b[q]  = *(const half8*)(ldsB + pl + 8192 + q * 512 + boff);             \
    ST2;                                                                      \
    BAR();                                                                    \
    __builtin_amdgcn_s_setprio(1);                                            \
    _Pragma("unroll") for (int q = 0; q < 4; ++q) {                           \
      acc[q][0] = MFMA16(a0[q], b[0], acc[q][0]);                             \
      acc[q][1] = MFMA16(a0[q], b[1], acc[q][1]);                             \
      acc[q][2] = MFMA16(a0[q], b[2], acc[q][2]);                             \
      acc[q][3] = MFMA16(a0[q], b[3], acc[q][3]);                             \
    }                                                                         \
    __builtin_amdgcn_s_setprio(0);                                            \
    BAR();                                                                    \
    /* ---- p3: kh1, mi 4-7 ---- */                                           \
    _Pragma("unroll") for (int q = 0; q < 4; ++q)                             \
      a1[q] = *(const half8*)(ldsA + pl + 8192 + 2048 + q * 512 + aoff);      \
    ST3;                                                                      \
    BAR();                                                                    \
    __builtin_amdgcn_s_setprio(1);                                            \
    _Pragma("unroll") for (int q = 0; q < 4; ++q) {                           \
      acc[4 + q][0] = MFMA16(a1[q], b[0], acc[4 + q][0]);                     \
      acc[4 + q][1] = MFMA16(a1[q], b[1], acc[4 + q][1]);                     \
      acc[4 + q][2] = MFMA16(a1[q], b[2], acc[4 + q][2]);                     \
      acc[4 + q][3] = MFMA16(a1[q], b[3], acc[4 + q][3]);                     \
    }                                                                         \
    __builtin_amdgcn_s_setprio(0);                                            \
    W2;                                                                       \
    BAR();                                                                    \
  } while (0)

  // prologue: virtual steady-state issue history for tiles 0,1 (7 units),
  // then wait for tile-0 kh0 units (oldest 4 loads) -> vmcnt(10).
  STAGE_B(0, 0); STAGE_A(0, 0); STAGE_B(0, 1); STAGE_A(0, 1);
  STAGE_B(1, 0); STAGE_A(1, 0); STAGE_B(1, 1);
  VM10;
  BAR();

  for (int t = 0; t < 14; ++t) {
    KTILE((t & 1),
          STAGE_A(t + 1, 1), STAGE_B(t + 2, 0),
          STAGE_A(t + 2, 0), STAGE_B(t + 2, 1),
          VM10, VM10);
  }
  // t = 14: only A(15,k1) remains to stage; waits shrink (fewer in flight).
  KTILE(0, STAGE_A(15, 1), (void)0, (void)0, (void)0, VM8, VM4);
  // t = 15: nothing to stage; p2 needs all remaining loads done.
  KTILE(1, (void)0, (void)0, (void)0, (void)0, VM0, (void)0);

  // epilogue: C/D layout col=lane&15, row=(lane>>4)*4+p
  int   gn[4];
  float bs[4], sp[4];
#pragma unroll
  for (int nj = 0; nj < 4; ++nj) {
    gn[nj] = n0 + wn * 64 + nj * 16 + l15;
    bs[nj] = bias[gn[nj]];
    sp[nj] = 0.f;
    if (MODE == 1 && gn[nj] >= 1024)
      sp[nj] = log1pf(expf(a_param[gn[nj] - 1024]));   // softplus
  }
#pragma unroll
  for (int mi = 0; mi < 8; ++mi) {
#pragma unroll
    for (int p = 0; p < 4; ++p) {
      int gm = m0 + wm * 128 + mi * 16 + g * 4 + p;
      size_t rowb = (size_t)gm * 2048;
#pragma unroll
      for (int nj = 0; nj < 4; ++nj) {
        float v = acc[mi][nj][p] + bs[nj];
        if (MODE == 1) {
          float s = 1.f / (1.f + expf(-v));
          if (gn[nj] < 1024) {
            v = s;                          // gate_x
          } else {
            float av = expf(-8.f * s * sp[nj]);
            if ((gm & (T_ - 1)) == 0) av = 0.f;   // t == 0
            v = av;
          }
        }
        C[rowb + gn[nj]] = (_Float16)v;
      }
    }
  }
#undef STAGE_A
#undef STAGE_B
#undef KTILE
}

// ---------------- conv: x2 = sum_j cw[3-j]*x1[t-j] + cb ---------------------
__global__ __launch_bounds__(256) void conv_kernel(
    const _Float16* __restrict__ g1, const float* __restrict__ cw,
    const float* __restrict__ cb, _Float16* __restrict__ x2) {
  int idx = blockIdx.x * 256 + threadIdx.x;   // over M_*H_/8
  int m  = idx >> 7;
  int hb = (idx & 127) * 8;
  int t  = m & (T_ - 1);
  float acc[8];
#pragma unroll
  for (int e = 0; e < 8; ++e) acc[e] = cb[hb + e];
#pragma unroll
  for (int j = 0; j < 4; ++j) {
    if (t >= j) {
      half8 xv = *(const half8*)&g1[(size_t)(m - j) * 2048 + hb];
      const float* w = &cw[(3 - j) * 1024 + hb];
#pragma unroll
      for (int e = 0; e < 8; ++e) acc[e] += w[e] * (float)xv[e];
    }
  }
  half8 o;
#pragma unroll
  for (int e = 0; e < 8; ++e) o[e] = (_Float16)acc[e];
  *(half8*)&x2[(size_t)m * 1024 + hb] = o;
}

// ---------------- scan pass 1: per-chunk (prod a, local h) ------------------
__global__ __launch_bounds__(128) void scan1_kernel(
    const _Float16* __restrict__ g2, const _Float16* __restrict__ x2,
    float* __restrict__ cA, float* __restrict__ cH) {
  int bid = blockIdx.x;          // b*NC_ + c
  int b = bid >> 7, c = bid & 127;
  int h0 = threadIdx.x * 8;
  float A[8], Hh[8];
#pragma unroll
  for (int e = 0; e < 8; ++e) { A[e] = 1.f; Hh[e] = 0.f; }
  size_t mbase = (size_t)b * T_ + (size_t)c * CL_;
  for (int i = 0; i < CL_; ++i) {
    size_t m = mbase + i;
    half8 gx = *(const half8*)&g2[m * 2048 + h0];
    half8 av = *(const half8*)&g2[m * 2048 + 1024 + h0];
    half8 xv = *(const half8*)&x2[m * 1024 + h0];
#pragma unroll
    for (int e = 0; e < 8; ++e) {
      float a = (float)av[e];
      float mult = sqrtf(fmaxf(1.f - a * a, 0.f));
      float nx = (float)gx[e] * (float)xv[e] * mult;
      A[e] *= a;
      Hh[e] = nx + a * Hh[e];
    }
  }
  size_t o = (size_t)bid * 1024 + h0;
#pragma unroll
  for (int e = 0; e < 8; ++e) { cA[o + e] = A[e]; cH[o + e] = Hh[e]; }
}

// ---------------- scan pass 2: carries across chunks ------------------------
__global__ void scanmid_kernel(const float* __restrict__ cA,
                               const float* __restrict__ cH,
                               float* __restrict__ carry) {
  int gidx = blockIdx.x * 256 + threadIdx.x;  // 8192 = B_*H_
  int b = gidx >> 10, h = gidx & 1023;
  float run = 0.f;
  for (int c = 0; c < NC_; ++c) {
    size_t o = ((size_t)(b * NC_ + c)) * 1024 + h;
    carry[o] = run;
    run = cH[o] + cA[o] * run;
  }
}

// ---------------- scan pass 3: h, out = h*gelu(u), hn -----------------------
__global__ __launch_bounds__(128) void scan2_kernel(
    const _Float16* __restrict__ g2, const _Float16* __restrict__ x2,
    const _Float16* __restrict__ g1, const float* __restrict__ carry,
    float* __restrict__ outO, float* __restrict__ outH,
    float* __restrict__ outHn) {
  int bid = blockIdx.x;
  int b = bid >> 7, c = bid & 127;
  int h0 = threadIdx.x * 8;
  float Hh[8];
  {
    size_t o = (size_t)bid * 1024 + h0;
#pragma unroll
    for (int e = 0; e < 8; ++e) Hh[e] = carry[o + e];
  }
  size_t mbase = (size_t)b * T_ + (size_t)c * CL_;
  for (int i = 0; i < CL_; ++i) {
    size_t m = mbase + i;
    half8 gx = *(const half8*)&g2[m * 2048 + h0];
    half8 av = *(const half8*)&g2[m * 2048 + 1024 + h0];
    half8 xv = *(const half8*)&x2[m * 1024 + h0];
    half8 uv = *(const half8*)&g1[m * 2048 + 1024 + h0];
    f32x4 hO[2], oO[2];
#pragma unroll
    for (int e = 0; e < 8; ++e) {
      float a = (float)av[e];
      float mult = sqrtf(fmaxf(1.f - a * a, 0.f));
      float nx = (float)gx[e] * (float)xv[e] * mult;
      float v = nx + a * Hh[e];
      Hh[e] = v;
      float u = (float)uv[e];
      float y = 0.5f * u * (1.f + erff(u * 0.70710678118654752f));  // exact gelu
      hO[e >> 2][e & 3] = v;
      oO[e >> 2][e & 3] = v * y;
    }
    size_t ob = m * 1024 + h0;
    *(f32x4*)&outH[ob]     = hO[0];
    *(f32x4*)&outH[ob + 4] = hO[1];
    *(f32x4*)&outO[ob]     = oO[0];
    *(f32x4*)&outO[ob + 4] = oO[1];
  }
  if (c == NC_ - 1) {
    size_t o = (size_t)b * 1024 + h0;
#pragma unroll
    for (int e = 0; e < 8; ++e) outHn[o + e] = Hh[e];
  }
}

// ---------------------------------------------------------------------------
extern "C" void kernel_launch(void* const* d_in, const int* in_sizes, int n_in,
                              void* d_out, int out_size, void* d_ws,
                              size_t ws_size, hipStream_t stream) {
  const float* x   = (const float*)d_in[0];
  const float* wx  = (const float*)d_in[1];
  const float* bx  = (const float*)d_in[2];
  const float* wy  = (const float*)d_in[3];
  const float* by  = (const float*)d_in[4];
  const float* cw  = (const float*)d_in[5];
  const float* cb  = (const float*)d_in[6];
  const float* giw = (const float*)d_in[7];
  const float* gib = (const float*)d_in[8];
  const float* gaw = (const float*)d_in[9];
  const float* gab = (const float*)d_in[10];
  const float* ap  = (const float*)d_in[11];

  char* ws = (char*)d_ws;
  size_t off = 0;
  auto alloc = [&](size_t bytes) {
    char* p = ws + off;
    off += (bytes + 255) & ~(size_t)255;
    return p;
  };
  _Float16* wT1 = (_Float16*)alloc((size_t)2048 * 1024 * 2);  // [n][k] fp16
  _Float16* wT2 = (_Float16*)alloc((size_t)2048 * 1024 * 2);
  float*    b1  = (float*)alloc(2048 * 4);
  float*    b2  = (float*)alloc(2048 * 4);
  _Float16* xh  = (_Float16*)alloc((size_t)M_ * 1024 * 2);  // x fp16; aliased
  _Float16* g2e = (_Float16*)alloc((size_t)M_ * 1024 * 2);  // extension
  (void)g2e;
  _Float16* g1o = (_Float16*)alloc((size_t)M_ * 2048 * 2);  // [x1 | u]
  _Float16* x2h = (_Float16*)alloc((size_t)M_ * 1024 * 2);  // x2
  float* cA  = (float*)alloc((size_t)B_ * NC_ * 1024 * 4);
  float* cH  = (float*)alloc((size_t)B_ * NC_ * 1024 * 4);
  float* cin = (float*)alloc((size_t)B_ * NC_ * 1024 * 4);
  _Float16* g2o = xh;  // [gx | a], 134MB spanning xh+g2e (xh dead by then)

  float* oO  = (float*)d_out;
  float* oH  = oO + (size_t)M_ * 1024;
  float* oHn = oO + (size_t)2 * M_ * 1024;

  transpose_cvt<<<dim3(64, 32), 256, 0, stream>>>(wx, wy, wT1);
  transpose_cvt<<<dim3(64, 32), 256, 0, stream>>>(giw, gaw, wT2);
  prep_bias<<<4, 1024, 0, stream>>>(bx, by, gib, gab, b1, b2);
  cvt_fp16<<<2048, 256, 0, stream>>>(x, xh, (long)M_ * 1024 / 4);

  gemm_kernel<0><<<1024, 512, 0, stream>>>(xh, wT1, b1, nullptr, g1o);
  conv_kernel<<<16384, 256, 0, stream>>>(g1o, cw, cb, x2h);
  gemm_kernel<1><<<1024, 512, 0, stream>>>(x2h, wT2, b2, ap, g2o);

  scan1_kernel<<<B_ * NC_, 128, 0, stream>>>(g2o, x2h, cA, cH);
  scanmid_kernel<<<32, 256, 0, stream>>>(cA, cH, cin);
  scan2_kernel<<<B_ * NC_, 128, 0, stream>>>(g2o, x2h, g1o, cin, oO, oH, oHn);
}

// Round 5
// 627.319 us; speedup vs baseline: 1.0018x; 1.0018x over previous
//
#include <hip/hip_runtime.h>
#include <math.h>

// ---------------------------------------------------------------------------
// GriffinRecurrentBlock. R5: same 256x256 8-wave counted-vmcnt GEMM as R4,
// but with the fence poison removed: raw s_barrier (no "memory"-clobber asm
// around it) and clobber-free s_waitcnt vmcnt(N) pinned with sched_barrier(0).
// R3/R4's asm(:::"memory") forced the waitcnt pass to drain vmcnt(0) at every
// barrier (global_load_lds writes LDS = "memory"), serializing every phase on
// staging latency -- which is why counted vmcnt measured == drain.
// ---------------------------------------------------------------------------

#define B_ 8
#define T_ 4096
#define H_ 1024
#define M_ (B_ * T_)          // 32768
#define NC_ 128               // chunks per sequence
#define CL_ 32                // chunk length (T_/NC_)

typedef _Float16 half8 __attribute__((ext_vector_type(8)));
typedef _Float16 half4 __attribute__((ext_vector_type(4)));
typedef float    f32x4 __attribute__((ext_vector_type(4)));

#define BAR() __builtin_amdgcn_s_barrier()
#define SCHED0 __builtin_amdgcn_sched_barrier(0)
#define VMW(N) do { asm volatile("s_waitcnt vmcnt(" #N ")"); SCHED0; } while (0)
#define MFMA16(a, b, c) __builtin_amdgcn_mfma_f32_16x16x32_f16((a), (b), (c), 0, 0, 0)

__device__ __forceinline__ void load16_lds(const _Float16* g, _Float16* l) {
  __builtin_amdgcn_global_load_lds(
      (const __attribute__((address_space(1))) void*)g,
      (__attribute__((address_space(3))) void*)l, 16, 0, 0);
}

// ---------------- prep: 32x32 LDS transpose + fp32->fp16 -------------------
__global__ __launch_bounds__(256) void transpose_cvt(
    const float* __restrict__ sA, const float* __restrict__ sB,
    _Float16* __restrict__ dst) {
  __shared__ float tile[32][33];
  int bn = blockIdx.x * 32;
  int bk = blockIdx.y * 32;
  const float* src = (bn < 1024) ? sA : sB;
  int nof = (bn < 1024) ? bn : bn - 1024;
  int c  = threadIdx.x & 31;
  int r0 = threadIdx.x >> 5;
#pragma unroll
  for (int i = 0; i < 4; ++i) {
    int r = r0 + i * 8;
    tile[r][c] = src[(size_t)(bk + r) * 1024 + nof + c];
  }
  __syncthreads();
#pragma unroll
  for (int i = 0; i < 4; ++i) {
    int nl = r0 + i * 8;
    dst[(size_t)(bn + nl) * 1024 + bk + c] = (_Float16)tile[c][nl];
  }
}

__global__ void prep_bias(const float* __restrict__ bx, const float* __restrict__ by,
                          const float* __restrict__ gib, const float* __restrict__ gab,
                          float* __restrict__ b1, float* __restrict__ b2) {
  int i = blockIdx.x * 1024 + threadIdx.x;   // 0..4095
  if (i < 1024)      b1[i] = bx[i];
  else if (i < 2048) b1[i] = by[i - 1024];
  else if (i < 3072) b2[i - 2048] = gib[i - 2048];
  else               b2[i - 2048] = gab[i - 3072];
}

__global__ __launch_bounds__(256) void cvt_fp16(
    const float* __restrict__ x, _Float16* __restrict__ xh, long n4) {
  for (long i = (long)blockIdx.x * 256 + threadIdx.x; i < n4;
       i += (long)gridDim.x * 256) {
    f32x4 v = ((const f32x4*)x)[i];
    half4 h;
#pragma unroll
    for (int e = 0; e < 4; ++e) h[e] = (_Float16)v[e];
    ((half4*)xh)[i] = h;
  }
}

// ---------------- GEMM: C[M][2048] = A[M][1024] * Bt[2048][1024]^T ----------
// 256x256 tile, 8 waves (2m x 4n), per-wave 128x64, BK=64, 16 K-tiles.
// LDS units: A[slot][kh], B[slot][kh] (slot = kt&1), each 256 rows x 32 halfs.
// Per K-tile phases (16 MFMA each):
//   p0: read A(kh0,mi0-3)+B(kh0,nj0-3); stage A(t+1,k1); MFMA
//   p1: read A(kh0,mi4-7);              stage B(t+2,k0); MFMA; vmcnt(10)
//   p2: read A(kh1,mi0-3)+B(kh1,nj0-3); stage A(t+2,k0); MFMA
//   p3: read A(kh1,mi4-7);              stage B(t+2,k1); MFMA; vmcnt(10)
// Stage of each unit lands exactly 1 phase after its slot's last read.
template <int MODE>
__global__ __launch_bounds__(512, 2) void gemm_kernel(
    const _Float16* __restrict__ A, const _Float16* __restrict__ Bt,
    const float* __restrict__ bias, const float* __restrict__ a_param,
    _Float16* __restrict__ C) {
  __shared__ _Float16 ldsA[32768];   // 64 KB: [slot][kh] 4 units of 8192
  __shared__ _Float16 ldsB[32768];   // 64 KB
  int tid  = threadIdx.x;
  int lane = tid & 63;
  int wave = tid >> 6;
  int l15 = lane & 15, g = lane >> 4;

  // XCD-bijective swizzle (grid = 1024 = 8*128)
  int nb = ((int)blockIdx.x & 7) * 128 + ((int)blockIdx.x >> 3);
  int m0 = (nb >> 3) * 256;           // 128 m-tiles
  int n0 = (nb & 7) * 256;            // 8 n-tiles
  int wm = wave >> 2;                 // 0..1
  int wn = wave & 3;                  // 0..3

  // --- staging: thread -> row (tid>>2), phys 16B-block (tid&3);
  //     global block = phys ^ f(row), f(row) = (row>>1)&3 = (tid>>3)&3.
  int gsrc = (tid & 3) ^ ((tid >> 3) & 3);
  const _Float16* pA = A  + (size_t)(m0 + (tid >> 2)) * 1024 + gsrc * 8;
  const _Float16* pB = Bt + (size_t)(n0 + (tid >> 2)) * 1024 + gsrc * 8;
  _Float16* stA = ldsA + wave * 512;  // HW adds lane*16B
  _Float16* stB = ldsB + wave * 512;

#define STAGE_A(kt, kh)                                                       \
  do {                                                                        \
    const _Float16* s_ = pA + (kt) * 64 + (kh) * 32;                          \
    _Float16* d_ = stA + (((kt) & 1) * 2 + (kh)) * 8192;                      \
    load16_lds(s_, d_);                    /* rows   0..127 */                \
    load16_lds(s_ + 131072, d_ + 4096);    /* rows 128..255 */                \
  } while (0)
#define STAGE_B(kt, kh)                                                       \
  do {                                                                        \
    const _Float16* s_ = pB + (kt) * 64 + (kh) * 32;                          \
    _Float16* d_ = stB + (((kt) & 1) * 2 + (kh)) * 8192;                      \
    load16_lds(s_, d_);                                                       \
    load16_lds(s_ + 131072, d_ + 4096);                                       \
  } while (0)

  // --- fragment read offsets (halfs): row r at r*32, block j = g ^ f(r),
  //     f(r) = (r>>1)&3 = (l15>>1)&3 (mi/nj/wm multiples of 4 rows drop out).
  int jj8  = ((g ^ ((l15 >> 1) & 3)) << 3);
  int aoff = wm * 4096 + l15 * 32 + jj8;   // + slot*16384 + kh*8192 + mi*512
  int boff = wn * 2048 + l15 * 32 + jj8;   // + slot*16384 + kh*8192 + nj*512

  f32x4 acc[8][4];
#pragma unroll
  for (int i = 0; i < 8; ++i)
#pragma unroll
    for (int j = 0; j < 4; ++j) acc[i][j] = (f32x4){0.f, 0.f, 0.f, 0.f};

  half8 a0[4], a1[4], b[4];

#define KTILE(SL, ST0, ST1, ST2, ST3, W1, W2)                                 \
  do {                                                                        \
    const int pl = (SL) * 16384;                                              \
    /* ---- p0: kh0, mi 0-3 ---- */                                           \
    _Pragma("unroll") for (int q = 0; q < 4; ++q)                             \
      a0[q] = *(const half8*)(ldsA + pl + q * 512 + aoff);                    \
    _Pragma("unroll") for (int q = 0; q < 4; ++q)                             \
      b[q]  = *(const half8*)(ldsB + pl + q * 512 + boff);                    \
    ST0;                                                                      \
    BAR();                                                                    \
    __builtin_amdgcn_s_setprio(1);                                            \
    _Pragma("unroll") for (int q = 0; q < 4; ++q) {                           \
      acc[q][0] = MFMA16(a0[q], b[0], acc[q][0]);                             \
      acc[q][1] = MFMA16(a0[q], b[1], acc[q][1]);                             \
      acc[q][2] = MFMA16(a0[q], b[2], acc[q][2]);                             \
      acc[q][3] = MFMA16(a0[q], b[3], acc[q][3]);                             \
    }                                                                         \
    __builtin_amdgcn_s_setprio(0);                                            \
    BAR();                                                                    \
    /* ---- p1: kh0, mi 4-7 ---- */                                           \
    _Pragma("unroll") for (int q = 0; q < 4; ++q)                             \
      a1[q] = *(const half8*)(ldsA + pl + 2048 + q * 512 + aoff);             \
    ST1;                                                                      \
    BAR();                                                                    \
    __builtin_amdgcn_s_setprio(1);                                            \
    _Pragma("unroll") for (int q = 0; q < 4; ++q) {                           \
      acc[4 + q][0] = MFMA16(a1[q], b[0], acc[4 + q][0]);                     \
      acc[4 + q][1] = MFMA16(a1[q], b[1], acc[4 + q][1]);                     \
      acc[4 + q][2] = MFMA16(a1[q], b[2], acc[4 + q][2]);                     \
      acc[4 + q][3] = MFMA16(a1[q], b[3], acc[4 + q][3]);                     \
    }                                                                         \
    __builtin_amdgcn_s_setprio(0);                                            \
    W1;                                                                       \
    BAR();                                                                    \
    /* ---- p2: kh1, mi 0-3 ---- */                                           \
    _Pragma("unroll") for (int q = 0; q < 4; ++q)                             \
      a0[q] = *(const half8*)(ldsA + pl + 8192 + q * 512 + aoff);             \
    _Pragma("unroll") for (int q = 0; q < 4; ++q)                             \
      b[q]  = *(const half8*)(ldsB + pl + 8192 + q * 512 + boff);             \
    ST2;                                                                      \
    BAR();                                                                    \
    __builtin_amdgcn_s_setprio(1);                                            \
    _Pragma("unroll") for (int q = 0; q < 4; ++q) {                           \
      acc[q][0] = MFMA16(a0[q], b[0], acc[q][0]);                             \
      acc[q][1] = MFMA16(a0[q], b[1], acc[q][1]);                             \
      acc[q][2] = MFMA16(a0[q], b[2], acc[q][2]);                             \
      acc[q][3] = MFMA16(a0[q], b[3], acc[q][3]);                             \
    }                                                                         \
    __builtin_amdgcn_s_setprio(0);                                            \
    BAR();                                                                    \
    /* ---- p3: kh1, mi 4-7 ---- */                                           \
    _Pragma("unroll") for (int q = 0; q < 4; ++q)                             \
      a1[q] = *(const half8*)(ldsA + pl + 8192 + 2048 + q * 512 + aoff);      \
    ST3;                                                                      \
    BAR();                                                                    \
    __builtin_amdgcn_s_setprio(1);                                            \
    _Pragma("unroll") for (int q = 0; q < 4; ++q) {                           \
      acc[4 + q][0] = MFMA16(a1[q], b[0], acc[4 + q][0]);                     \
      acc[4 + q][1] = MFMA16(a1[q], b[1], acc[4 + q][1]);                     \
      acc[4 + q][2] = MFMA16(a1[q], b[2], acc[4 + q][2]);                     \
      acc[4 + q][3] = MFMA16(a1[q], b[3], acc[4 + q][3]);                     \
    }                                                                         \
    __builtin_amdgcn_s_setprio(0);                                            \
    W2;                                                                       \
    BAR();                                                                    \
  } while (0)

  // prologue: virtual steady-state issue history for tiles 0,1 (7 units),
  // then wait for tile-0 kh0 units (oldest 4 loads) -> vmcnt(10).
  STAGE_B(0, 0); STAGE_A(0, 0); STAGE_B(0, 1); STAGE_A(0, 1);
  STAGE_B(1, 0); STAGE_A(1, 0); STAGE_B(1, 1);
  VMW(10);
  BAR();

  for (int t = 0; t < 14; ++t) {
    KTILE((t & 1),
          STAGE_A(t + 1, 1), STAGE_B(t + 2, 0),
          STAGE_A(t + 2, 0), STAGE_B(t + 2, 1),
          VMW(10), VMW(10));
  }
  // t = 14: only A(15,k1) remains to stage; waits shrink (fewer in flight).
  KTILE(0, STAGE_A(15, 1), (void)0, (void)0, (void)0, VMW(8), VMW(4));
  // t = 15: nothing to stage; p2 needs all remaining loads done.
  KTILE(1, (void)0, (void)0, (void)0, (void)0, VMW(0), (void)0);

  // epilogue: C/D layout col=lane&15, row=(lane>>4)*4+p
  int   gn[4];
  float bs[4], sp[4];
#pragma unroll
  for (int nj = 0; nj < 4; ++nj) {
    gn[nj] = n0 + wn * 64 + nj * 16 + l15;
    bs[nj] = bias[gn[nj]];
    sp[nj] = 0.f;
    if (MODE == 1 && gn[nj] >= 1024)
      sp[nj] = log1pf(expf(a_param[gn[nj] - 1024]));   // softplus
  }
#pragma unroll
  for (int mi = 0; mi < 8; ++mi) {
#pragma unroll
    for (int p = 0; p < 4; ++p) {
      int gm = m0 + wm * 128 + mi * 16 + g * 4 + p;
      size_t rowb = (size_t)gm * 2048;
#pragma unroll
      for (int nj = 0; nj < 4; ++nj) {
        float v = acc[mi][nj][p] + bs[nj];
        if (MODE == 1) {
          float s = 1.f / (1.f + expf(-v));
          if (gn[nj] < 1024) {
            v = s;                          // gate_x
          } else {
            float av = expf(-8.f * s * sp[nj]);
            if ((gm & (T_ - 1)) == 0) av = 0.f;   // t == 0
            v = av;
          }
        }
        C[rowb + gn[nj]] = (_Float16)v;
      }
    }
  }
#undef STAGE_A
#undef STAGE_B
#undef KTILE
}

// ---------------- conv: x2 = sum_j cw[3-j]*x1[t-j] + cb ---------------------
__global__ __launch_bounds__(256) void conv_kernel(
    const _Float16* __restrict__ g1, const float* __restrict__ cw,
    const float* __restrict__ cb, _Float16* __restrict__ x2) {
  int idx = blockIdx.x * 256 + threadIdx.x;   // over M_*H_/8
  int m  = idx >> 7;
  int hb = (idx & 127) * 8;
  int t  = m & (T_ - 1);
  float acc[8];
#pragma unroll
  for (int e = 0; e < 8; ++e) acc[e] = cb[hb + e];
#pragma unroll
  for (int j = 0; j < 4; ++j) {
    if (t >= j) {
      half8 xv = *(const half8*)&g1[(size_t)(m - j) * 2048 + hb];
      const float* w = &cw[(3 - j) * 1024 + hb];
#pragma unroll
      for (int e = 0; e < 8; ++e) acc[e] += w[e] * (float)xv[e];
    }
  }
  half8 o;
#pragma unroll
  for (int e = 0; e < 8; ++e) o[e] = (_Float16)acc[e];
  *(half8*)&x2[(size_t)m * 1024 + hb] = o;
}

// ---------------- scan pass 1: per-chunk (prod a, local h) ------------------
__global__ __launch_bounds__(128) void scan1_kernel(
    const _Float16* __restrict__ g2, const _Float16* __restrict__ x2,
    float* __restrict__ cA, float* __restrict__ cH) {
  int bid = blockIdx.x;          // b*NC_ + c
  int b = bid >> 7, c = bid & 127;
  int h0 = threadIdx.x * 8;
  float A[8], Hh[8];
#pragma unroll
  for (int e = 0; e < 8; ++e) { A[e] = 1.f; Hh[e] = 0.f; }
  size_t mbase = (size_t)b * T_ + (size_t)c * CL_;
  for (int i = 0; i < CL_; ++i) {
    size_t m = mbase + i;
    half8 gx = *(const half8*)&g2[m * 2048 + h0];
    half8 av = *(const half8*)&g2[m * 2048 + 1024 + h0];
    half8 xv = *(const half8*)&x2[m * 1024 + h0];
#pragma unroll
    for (int e = 0; e < 8; ++e) {
      float a = (float)av[e];
      float mult = sqrtf(fmaxf(1.f - a * a, 0.f));
      float nx = (float)gx[e] * (float)xv[e] * mult;
      A[e] *= a;
      Hh[e] = nx + a * Hh[e];
    }
  }
  size_t o = (size_t)bid * 1024 + h0;
#pragma unroll
  for (int e = 0; e < 8; ++e) { cA[o + e] = A[e]; cH[o + e] = Hh[e]; }
}

// ---------------- scan pass 2: carries across chunks ------------------------
__global__ void scanmid_kernel(const float* __restrict__ cA,
                               const float* __restrict__ cH,
                               float* __restrict__ carry) {
  int gidx = blockIdx.x * 256 + threadIdx.x;  // 8192 = B_*H_
  int b = gidx >> 10, h = gidx & 1023;
  float run = 0.f;
  for (int c = 0; c < NC_; ++c) {
    size_t o = ((size_t)(b * NC_ + c)) * 1024 + h;
    carry[o] = run;
    run = cH[o] + cA[o] * run;
  }
}

// ---------------- scan pass 3: h, out = h*gelu(u), hn -----------------------
__global__ __launch_bounds__(128) void scan2_kernel(
    const _Float16* __restrict__ g2, const _Float16* __restrict__ x2,
    const _Float16* __restrict__ g1, const float* __restrict__ carry,
    float* __restrict__ outO, float* __restrict__ outH,
    float* __restrict__ outHn) {
  int bid = blockIdx.x;
  int b = bid >> 7, c = bid & 127;
  int h0 = threadIdx.x * 8;
  float Hh[8];
  {
    size_t o = (size_t)bid * 1024 + h0;
#pragma unroll
    for (int e = 0; e < 8; ++e) Hh[e] = carry[o + e];
  }
  size_t mbase = (size_t)b * T_ + (size_t)c * CL_;
  for (int i = 0; i < CL_; ++i) {
    size_t m = mbase + i;
    half8 gx = *(const half8*)&g2[m * 2048 + h0];
    half8 av = *(const half8*)&g2[m * 2048 + 1024 + h0];
    half8 xv = *(const half8*)&x2[m * 1024 + h0];
    half8 uv = *(const half8*)&g1[m * 2048 + 1024 + h0];
    f32x4 hO[2], oO[2];
#pragma unroll
    for (int e = 0; e < 8; ++e) {
      float a = (float)av[e];
      float mult = sqrtf(fmaxf(1.f - a * a, 0.f));
      float nx = (float)gx[e] * (float)xv[e] * mult;
      float v = nx + a * Hh[e];
      Hh[e] = v;
      float u = (float)uv[e];
      float y = 0.5f * u * (1.f + erff(u * 0.70710678118654752f));  // exact gelu
      hO[e >> 2][e & 3] = v;
      oO[e >> 2][e & 3] = v * y;
    }
    size_t ob = m * 1024 + h0;
    *(f32x4*)&outH[ob]     = hO[0];
    *(f32x4*)&outH[ob + 4] = hO[1];
    *(f32x4*)&outO[ob]     = oO[0];
    *(f32x4*)&outO[ob + 4] = oO[1];
  }
  if (c == NC_ - 1) {
    size_t o = (size_t)b * 1024 + h0;
#pragma unroll
    for (int e = 0; e < 8; ++e) outHn[o + e] = Hh[e];
  }
}

// ---------------------------------------------------------------------------
extern "C" void kernel_launch(void* const* d_in, const int* in_sizes, int n_in,
                              void* d_out, int out_size, void* d_ws,
                              size_t ws_size, hipStream_t stream) {
  const float* x   = (const float*)d_in[0];
  const float* wx  = (const float*)d_in[1];
  const float* bx  = (const float*)d_in[2];
  const float* wy  = (const float*)d_in[3];
  const float* by  = (const float*)d_in[4];
  const float* cw  = (const float*)d_in[5];
  const float* cb  = (const float*)d_in[6];
  const float* giw = (const float*)d_in[7];
  const float* gib = (const float*)d_in[8];
  const float* gaw = (const float*)d_in[9];
  const float* gab = (const float*)d_in[10];
  const float* ap  = (const float*)d_in[11];

  char* ws = (char*)d_ws;
  size_t off = 0;
  auto alloc = [&](size_t bytes) {
    char* p = ws + off;
    off += (bytes + 255) & ~(size_t)255;
    return p;
  };
  _Float16* wT1 = (_Float16*)alloc((size_t)2048 * 1024 * 2);  // [n][k] fp16
  _Float16* wT2 = (_Float16*)alloc((size_t)2048 * 1024 * 2);
  float*    b1  = (float*)alloc(2048 * 4);
  float*    b2  = (float*)alloc(2048 * 4);
  _Float16* xh  = (_Float16*)alloc((size_t)M_ * 1024 * 2);  // x fp16; aliased
  _Float16* g2e = (_Float16*)alloc((size_t)M_ * 1024 * 2);  // extension
  (void)g2e;
  _Float16* g1o = (_Float16*)alloc((size_t)M_ * 2048 * 2);  // [x1 | u]
  _Float16* x2h = (_Float16*)alloc((size_t)M_ * 1024 * 2);  // x2
  float* cA  = (float*)alloc((size_t)B_ * NC_ * 1024 * 4);
  float* cH  = (float*)alloc((size_t)B_ * NC_ * 1024 * 4);
  float* cin = (float*)alloc((size_t)B_ * NC_ * 1024 * 4);
  _Float16* g2o = xh;  // [gx | a], 134MB spanning xh+g2e (xh dead by then)

  float* oO  = (float*)d_out;
  float* oH  = oO + (size_t)M_ * 1024;
  float* oHn = oO + (size_t)2 * M_ * 1024;

  transpose_cvt<<<dim3(64, 32), 256, 0, stream>>>(wx, wy, wT1);
  transpose_cvt<<<dim3(64, 32), 256, 0, stream>>>(giw, gaw, wT2);
  prep_bias<<<4, 1024, 0, stream>>>(bx, by, gib, gab, b1, b2);
  cvt_fp16<<<2048, 256, 0, stream>>>(x, xh, (long)M_ * 1024 / 4);

  gemm_kernel<0><<<1024, 512, 0, stream>>>(xh, wT1, b1, nullptr, g1o);
  conv_kernel<<<16384, 256, 0, stream>>>(g1o, cw, cb, x2h);
  gemm_kernel<1><<<1024, 512, 0, stream>>>(x2h, wT2, b2, ap, g2o);

  scan1_kernel<<<B_ * NC_, 128, 0, stream>>>(g2o, x2h, cA, cH);
  scanmid_kernel<<<32, 256, 0, stream>>>(cA, cH, cin);
  scan2_kernel<<<B_ * NC_, 128, 0, stream>>>(g2o, x2h, g1o, cin, oO, oH, oHn);
}

// Round 8
// 622.381 us; speedup vs baseline: 1.0098x; 1.0079x over previous
//
#include <hip/hip_runtime.h>
#include <math.h>

// ---------------------------------------------------------------------------
// GriffinRecurrentBlock. R8: R6/R7's failure was NOT the gemm256 schedule --
// it was a transcription typo in the gemm128 "control" kernel (fragment
// stride mi*16 half8 = 4 rows instead of mi*64 = 16 rows; R2's passing
// original used mi*64). Fixed here. Everything else identical to R7:
//  GEMM1 = gemm256: 2-barrier-per-K-tile counted vmcnt(8) pipeline, sealed
//          WAITBAR = {waitcnt vmcnt(N) lgkmcnt(0); sched0; s_barrier; sched0}.
//  GEMM2 = gemm128: R2's m97-style kernel (true copy).  Per-dispatch A/B.
// ---------------------------------------------------------------------------

#define B_ 8
#define T_ 4096
#define H_ 1024
#define M_ (B_ * T_)          // 32768
#define NC_ 128               // chunks per sequence
#define CL_ 32                // chunk length (T_/NC_)

typedef _Float16 half8 __attribute__((ext_vector_type(8)));
typedef _Float16 half4 __attribute__((ext_vector_type(4)));
typedef float    f32x4 __attribute__((ext_vector_type(4)));

#define SCHED0 __builtin_amdgcn_sched_barrier(0)
#define WAITBAR(N)                                                            \
  do {                                                                        \
    asm volatile("s_waitcnt vmcnt(" #N ") lgkmcnt(0)");                       \
    SCHED0;                                                                   \
    __builtin_amdgcn_s_barrier();                                             \
    SCHED0;                                                                   \
  } while (0)
#define MFMA16(a, b, c) __builtin_amdgcn_mfma_f32_16x16x32_f16((a), (b), (c), 0, 0, 0)

__device__ __forceinline__ void load16_lds(const _Float16* g, _Float16* l) {
  __builtin_amdgcn_global_load_lds(
      (const __attribute__((address_space(1))) void*)g,
      (__attribute__((address_space(3))) void*)l, 16, 0, 0);
}

// ---------------- prep: 32x32 LDS transpose + fp32->fp16 -------------------
__global__ __launch_bounds__(256) void transpose_cvt(
    const float* __restrict__ sA, const float* __restrict__ sB,
    _Float16* __restrict__ dst) {
  __shared__ float tile[32][33];
  int bn = blockIdx.x * 32;
  int bk = blockIdx.y * 32;
  const float* src = (bn < 1024) ? sA : sB;
  int nof = (bn < 1024) ? bn : bn - 1024;
  int c  = threadIdx.x & 31;
  int r0 = threadIdx.x >> 5;
#pragma unroll
  for (int i = 0; i < 4; ++i) {
    int r = r0 + i * 8;
    tile[r][c] = src[(size_t)(bk + r) * 1024 + nof + c];
  }
  __syncthreads();
#pragma unroll
  for (int i = 0; i < 4; ++i) {
    int nl = r0 + i * 8;
    dst[(size_t)(bn + nl) * 1024 + bk + c] = (_Float16)tile[c][nl];
  }
}

__global__ void prep_bias(const float* __restrict__ bx, const float* __restrict__ by,
                          const float* __restrict__ gib, const float* __restrict__ gab,
                          float* __restrict__ b1, float* __restrict__ b2) {
  int i = blockIdx.x * 1024 + threadIdx.x;   // 0..4095
  if (i < 1024)      b1[i] = bx[i];
  else if (i < 2048) b1[i] = by[i - 1024];
  else if (i < 3072) b2[i - 2048] = gib[i - 2048];
  else               b2[i - 2048] = gab[i - 3072];
}

__global__ __launch_bounds__(256) void cvt_fp16(
    const float* __restrict__ x, _Float16* __restrict__ xh, long n4) {
  for (long i = (long)blockIdx.x * 256 + threadIdx.x; i < n4;
       i += (long)gridDim.x * 256) {
    f32x4 v = ((const f32x4*)x)[i];
    half4 h;
#pragma unroll
    for (int e = 0; e < 4; ++e) h[e] = (_Float16)v[e];
    ((half4*)xh)[i] = h;
  }
}

// ================= gemm256: 2-barrier-per-K-tile counted pipeline ===========
// C[M][2048] = A[M][1024] * Bt[2048][1024]^T. 256x256 tile, 8 waves (2m x 4n),
// BK=64, 16 K-tiles. LDS: A,B each 4 units of 16KB ([256 rows][32 halfs],
// 16B-block XOR swizzle j ^= (row>>1)&3, source-pre-permuted).
// Per K-tile: p0{read kh0 a0+b, stage(t+1,k1), 16 MFMA}
//             p1{read kh0 a1, 16 MFMA} WAITBAR(8)
//             p2{read kh1 a0+b, stage(t+2,k0), 16 MFMA}
//             p3{read kh1 a1, 16 MFMA} WAITBAR(8)
template <int MODE>
__global__ __launch_bounds__(512, 2) void gemm256_kernel(
    const _Float16* __restrict__ A, const _Float16* __restrict__ Bt,
    const float* __restrict__ bias, const float* __restrict__ a_param,
    _Float16* __restrict__ C) {
  __shared__ _Float16 ldsA[32768];   // 64 KB: [slot][kh] 4 units of 8192
  __shared__ _Float16 ldsB[32768];   // 64 KB
  int tid  = threadIdx.x;
  int lane = tid & 63;
  int wave = tid >> 6;
  int l15 = lane & 15, g = lane >> 4;

  // XCD-bijective swizzle (grid = 1024 = 8*128)
  int nb = ((int)blockIdx.x & 7) * 128 + ((int)blockIdx.x >> 3);
  int m0 = (nb >> 3) * 256;           // 128 m-tiles
  int n0 = (nb & 7) * 256;            // 8 n-tiles
  int wm = wave >> 2;                 // 0..1
  int wn = wave & 3;                  // 0..3

  // ---- epilogue constants FIRST (oldest vmcnt events; prologue wait absorbs
  //      them whether or not the compiler sinks them to the epilogue).
  int   gn[4];
  float bs[4], sp[4];
#pragma unroll
  for (int nj = 0; nj < 4; ++nj) {
    gn[nj] = n0 + wn * 64 + nj * 16 + l15;
    bs[nj] = bias[gn[nj]];
    sp[nj] = 0.f;
    if (MODE == 1 && gn[nj] >= 1024)
      sp[nj] = log1pf(expf(a_param[gn[nj] - 1024]));   // softplus
  }
  SCHED0;

  // ---- staging addressing: row = tid>>2, phys 16B-block tid&3,
  //      global block = (tid&3) ^ f(row), f(row) = (row>>1)&3 = (tid>>3)&3.
  int gsrc = (tid & 3) ^ ((tid >> 3) & 3);
  const _Float16* pA = A  + (size_t)(m0 + (tid >> 2)) * 1024 + gsrc * 8;
  const _Float16* pB = Bt + (size_t)(n0 + (tid >> 2)) * 1024 + gsrc * 8;
  _Float16* stA = ldsA + wave * 512;  // HW adds lane*16B
  _Float16* stB = ldsB + wave * 512;

#define STAGE_A(kt, kh)                                                       \
  do {                                                                        \
    const _Float16* s_ = pA + (kt) * 64 + (kh) * 32;                          \
    _Float16* d_ = stA + (((kt) & 1) * 2 + (kh)) * 8192;                      \
    load16_lds(s_, d_);                    /* rows   0..127 */                \
    load16_lds(s_ + 131072, d_ + 4096);    /* rows 128..255 */                \
  } while (0)
#define STAGE_B(kt, kh)                                                       \
  do {                                                                        \
    const _Float16* s_ = pB + (kt) * 64 + (kh) * 32;                          \
    _Float16* d_ = stB + (((kt) & 1) * 2 + (kh)) * 8192;                      \
    load16_lds(s_, d_);                                                       \
    load16_lds(s_ + 131072, d_ + 4096);                                       \
  } while (0)

  // ---- fragment read offsets (halfs): row r at r*32, block j = g ^ f(r);
  //      all row offsets are 16-multiples so f(r) depends only on l15.
  int jj8  = ((g ^ ((l15 >> 1) & 3)) << 3);
  int aoff = wm * 4096 + l15 * 32 + jj8;   // + slot*16384 + kh*8192 + mi*512
  int boff = wn * 2048 + l15 * 32 + jj8;   // + slot*16384 + kh*8192 + nj*512

  f32x4 acc[8][4];
#pragma unroll
  for (int i = 0; i < 8; ++i)
#pragma unroll
    for (int j = 0; j < 4; ++j) acc[i][j] = (f32x4){0.f, 0.f, 0.f, 0.f};

  half8 a0[4], a1[4], b[4];

#define KTILE(SL, ST0, ST2, WB1, WB2)                                         \
  do {                                                                        \
    const int pl = (SL) * 16384;                                              \
    /* ---- p0: kh0, mi 0-3 (+ stage next k1) ---- */                         \
    _Pragma("unroll") for (int q = 0; q < 4; ++q)                             \
      a0[q] = *(const half8*)(ldsA + pl + q * 512 + aoff);                    \
    _Pragma("unroll") for (int q = 0; q < 4; ++q)                             \
      b[q]  = *(const half8*)(ldsB + pl + q * 512 + boff);                    \
    ST0;                                                                      \
    __builtin_amdgcn_s_setprio(1);                                            \
    _Pragma("unroll") for (int q = 0; q < 4; ++q) {                           \
      acc[q][0] = MFMA16(a0[q], b[0], acc[q][0]);                             \
      acc[q][1] = MFMA16(a0[q], b[1], acc[q][1]);                             \
      acc[q][2] = MFMA16(a0[q], b[2], acc[q][2]);                             \
      acc[q][3] = MFMA16(a0[q], b[3], acc[q][3]);                             \
    }                                                                         \
    __builtin_amdgcn_s_setprio(0);                                            \
    /* ---- p1: kh0, mi 4-7 ---- */                                           \
    _Pragma("unroll") for (int q = 0; q < 4; ++q)                             \
      a1[q] = *(const half8*)(ldsA + pl + 2048 + q * 512 + aoff);             \
    __builtin_amdgcn_s_setprio(1);                                            \
    _Pragma("unroll") for (int q = 0; q < 4; ++q) {                           \
      acc[4 + q][0] = MFMA16(a1[q], b[0], acc[4 + q][0]);                     \
      acc[4 + q][1] = MFMA16(a1[q], b[1], acc[4 + q][1]);                     \
      acc[4 + q][2] = MFMA16(a1[q], b[2], acc[4 + q][2]);                     \
      acc[4 + q][3] = MFMA16(a1[q], b[3], acc[4 + q][3]);                     \
    }                                                                         \
    __builtin_amdgcn_s_setprio(0);                                            \
    WB1;                                                                      \
    /* ---- p2: kh1, mi 0-3 (+ stage next k0) ---- */                         \
    _Pragma("unroll") for (int q = 0; q < 4; ++q)                             \
      a0[q] = *(const half8*)(ldsA + pl + 8192 + q * 512 + aoff);             \
    _Pragma("unroll") for (int q = 0; q < 4; ++q)                             \
      b[q]  = *(const half8*)(ldsB + pl + 8192 + q * 512 + boff);             \
    ST2;                                                                      \
    __builtin_amdgcn_s_setprio(1);                                            \
    _Pragma("unroll") for (int q = 0; q < 4; ++q) {                           \
      acc[q][0] = MFMA16(a0[q], b[0], acc[q][0]);                             \
      acc[q][1] = MFMA16(a0[q], b[1], acc[q][1]);                             \
      acc[q][2] = MFMA16(a0[q], b[2], acc[q][2]);                             \
      acc[q][3] = MFMA16(a0[q], b[3], acc[q][3]);                             \
    }                                                                         \
    __builtin_amdgcn_s_setprio(0);                                            \
    /* ---- p3: kh1, mi 4-7 ---- */                                           \
    _Pragma("unroll") for (int q = 0; q < 4; ++q)                             \
      a1[q] = *(const half8*)(ldsA + pl + 8192 + 2048 + q * 512 + aoff);      \
    __builtin_amdgcn_s_setprio(1);                                            \
    _Pragma("unroll") for (int q = 0; q < 4; ++q) {                           \
      acc[4 + q][0] = MFMA16(a1[q], b[0], acc[4 + q][0]);                     \
      acc[4 + q][1] = MFMA16(a1[q], b[1], acc[4 + q][1]);                     \
      acc[4 + q][2] = MFMA16(a1[q], b[2], acc[4 + q][2]);                     \
      acc[4 + q][3] = MFMA16(a1[q], b[3], acc[4 + q][3]);                     \
    }                                                                         \
    __builtin_amdgcn_s_setprio(0);                                            \
    WB2;                                                                      \
  } while (0)

  // prologue: tile0 kh0/kh1 + tile1 kh0 in flight; wait completes at least
  // tile0 kh0 (oldest stage loads) regardless of bias-load placement.
  STAGE_A(0, 0); STAGE_B(0, 0);
  STAGE_A(0, 1); STAGE_B(0, 1);
  STAGE_A(1, 0); STAGE_B(1, 0);
  WAITBAR(8);

  for (int t = 0; t < 14; ++t) {
    KTILE((t & 1),
          { STAGE_A(t + 1, 1); STAGE_B(t + 1, 1); },
          { STAGE_A(t + 2, 0); STAGE_B(t + 2, 0); },
          WAITBAR(8), WAITBAR(8));
  }
  // t = 14: no (t+2) tile; second wait shrinks to vmcnt(4).
  KTILE(0, { STAGE_A(15, 1); STAGE_B(15, 1); }, (void)0, WAITBAR(8), WAITBAR(4));
  // t = 15: nothing to stage; first wait drains the last k1 units.
  KTILE(1, (void)0, (void)0, WAITBAR(0), (void)0);

  // epilogue: C/D layout col=lane&15, row=(lane>>4)*4+p
#pragma unroll
  for (int mi = 0; mi < 8; ++mi) {
#pragma unroll
    for (int p = 0; p < 4; ++p) {
      int gm = m0 + wm * 128 + mi * 16 + g * 4 + p;
      size_t rowb = (size_t)gm * 2048;
#pragma unroll
      for (int nj = 0; nj < 4; ++nj) {
        float v = acc[mi][nj][p] + bs[nj];
        if (MODE == 1) {
          float s = 1.f / (1.f + expf(-v));
          if (gn[nj] < 1024) {
            v = s;                          // gate_x
          } else {
            float av = expf(-8.f * s * sp[nj]);
            if ((gm & (T_ - 1)) == 0) av = 0.f;   // t == 0
            v = av;
          }
        }
        C[rowb + gn[nj]] = (_Float16)v;
      }
    }
  }
#undef STAGE_A
#undef STAGE_B
#undef KTILE
}

// ================= gemm128: R2's proven m97-style kernel (true copy) ========
// 128x128 tile, 4 waves (2x2 of 64x64), BK=32, linear LDS [row][32 halfs]
// (4 half8 per row -> fragment m-stride = 16 rows = 64 half8).
template <int MODE>
__global__ __launch_bounds__(256, 2) void gemm128_kernel(
    const _Float16* __restrict__ A, const _Float16* __restrict__ Bt,
    const float* __restrict__ bias, const float* __restrict__ a_param,
    _Float16* __restrict__ C) {
  __shared__ _Float16 sA[128 * 32];   // 8 KB
  __shared__ _Float16 sB[128 * 32];   // 8 KB
  const int K = 1024;
  int tid  = threadIdx.x;
  int lane = tid & 63;
  int wave = tid >> 6;

  int nb  = (int)blockIdx.x;
  int per = (int)gridDim.x >> 3;
  nb = (nb & 7) * per + (nb >> 3);
  int mtile = nb >> 4;                  // 256 m-tiles
  int ntile = nb & 15;                  // 16 n-tiles
  int m0 = mtile * 128, n0 = ntile * 128;
  int wm = wave >> 1, wn = wave & 1;

  int row0 = tid >> 2, kg0 = tid & 3;
  const _Float16* gA0 = A  + (size_t)(m0 + row0) * K + kg0 * 8;
  const _Float16* gA1 = gA0 + (size_t)64 * K;
  const _Float16* gB0 = Bt + (size_t)(n0 + row0) * K + kg0 * 8;
  const _Float16* gB1 = gB0 + (size_t)64 * K;
  _Float16* lA0 = sA + wave * 512;
  _Float16* lA1 = sA + 2048 + wave * 512;
  _Float16* lB0 = sB + wave * 512;
  _Float16* lB1 = sB + 2048 + wave * 512;

  f32x4 acc[4][4];
#pragma unroll
  for (int i = 0; i < 4; ++i)
#pragma unroll
    for (int j = 0; j < 4; ++j) acc[i][j] = (f32x4){0.f, 0.f, 0.f, 0.f};

  const half8* sA8 = (const half8*)sA;
  const half8* sB8 = (const half8*)sB;
  // fragment: lane l -> row (l&15), k-group (l>>4); row stride = 4 half8,
  // fragment m/n stride = 16 rows = 64 half8.  (R6/R7 typo'd this as 16.)
  int fa = (wm * 64 + (lane & 15)) * 4 + (lane >> 4);
  int fb = (wn * 64 + (lane & 15)) * 4 + (lane >> 4);

  for (int kk = 0; kk < 32; ++kk) {
    int ko = kk * 32;
    load16_lds(gA0 + ko, lA0);
    load16_lds(gA1 + ko, lA1);
    load16_lds(gB0 + ko, lB0);
    load16_lds(gB1 + ko, lB1);
    __syncthreads();
    half8 af[4], bf[4];
#pragma unroll
    for (int mi = 0; mi < 4; ++mi) af[mi] = sA8[fa + mi * 64];
#pragma unroll
    for (int ni = 0; ni < 4; ++ni) bf[ni] = sB8[fb + ni * 64];
#pragma unroll
    for (int mi = 0; mi < 4; ++mi)
#pragma unroll
      for (int ni = 0; ni < 4; ++ni)
        acc[mi][ni] = MFMA16(af[mi], bf[ni], acc[mi][ni]);
    __syncthreads();
  }

  int lr = lane >> 4;
  int lc = lane & 15;
  int   gn[4];
  float bs[4], sp[4];
#pragma unroll
  for (int ni = 0; ni < 4; ++ni) {
    gn[ni] = n0 + wn * 64 + ni * 16 + lc;
    bs[ni] = bias[gn[ni]];
    sp[ni] = 0.f;
    if (MODE == 1 && gn[ni] >= 1024)
      sp[ni] = log1pf(expf(a_param[gn[ni] - 1024]));
  }
#pragma unroll
  for (int mi = 0; mi < 4; ++mi) {
#pragma unroll
    for (int p = 0; p < 4; ++p) {
      int gm = m0 + wm * 64 + mi * 16 + lr * 4 + p;
      size_t rowb = (size_t)gm * 2048;
#pragma unroll
      for (int ni = 0; ni < 4; ++ni) {
        float v = acc[mi][ni][p] + bs[ni];
        if (MODE == 1) {
          float s = 1.f / (1.f + expf(-v));
          if (gn[ni] < 1024) {
            v = s;
          } else {
            float av = expf(-8.f * s * sp[ni]);
            if ((gm & (T_ - 1)) == 0) av = 0.f;
            v = av;
          }
        }
        C[rowb + gn[ni]] = (_Float16)v;
      }
    }
  }
}

// ---------------- conv: x2 = sum_j cw[3-j]*x1[t-j] + cb ---------------------
__global__ __launch_bounds__(256) void conv_kernel(
    const _Float16* __restrict__ g1, const float* __restrict__ cw,
    const float* __restrict__ cb, _Float16* __restrict__ x2) {
  int idx = blockIdx.x * 256 + threadIdx.x;   // over M_*H_/8
  int m  = idx >> 7;
  int hb = (idx & 127) * 8;
  int t  = m & (T_ - 1);
  float acc[8];
#pragma unroll
  for (int e = 0; e < 8; ++e) acc[e] = cb[hb + e];
#pragma unroll
  for (int j = 0; j < 4; ++j) {
    if (t >= j) {
      half8 xv = *(const half8*)&g1[(size_t)(m - j) * 2048 + hb];
      const float* w = &cw[(3 - j) * 1024 + hb];
#pragma unroll
      for (int e = 0; e < 8; ++e) acc[e] += w[e] * (float)xv[e];
    }
  }
  half8 o;
#pragma unroll
  for (int e = 0; e < 8; ++e) o[e] = (_Float16)acc[e];
  *(half8*)&x2[(size_t)m * 1024 + hb] = o;
}

// ---------------- scan pass 1: per-chunk (prod a, local h) ------------------
__global__ __launch_bounds__(128) void scan1_kernel(
    const _Float16* __restrict__ g2, const _Float16* __restrict__ x2,
    float* __restrict__ cA, float* __restrict__ cH) {
  int bid = blockIdx.x;          // b*NC_ + c
  int b = bid >> 7, c = bid & 127;
  int h0 = threadIdx.x * 8;
  float A[8], Hh[8];
#pragma unroll
  for (int e = 0; e < 8; ++e) { A[e] = 1.f; Hh[e] = 0.f; }
  size_t mbase = (size_t)b * T_ + (size_t)c * CL_;
  for (int i = 0; i < CL_; ++i) {
    size_t m = mbase + i;
    half8 gx = *(const half8*)&g2[m * 2048 + h0];
    half8 av = *(const half8*)&g2[m * 2048 + 1024 + h0];
    half8 xv = *(const half8*)&x2[m * 1024 + h0];
#pragma unroll
    for (int e = 0; e < 8; ++e) {
      float a = (float)av[e];
      float mult = sqrtf(fmaxf(1.f - a * a, 0.f));
      float nx = (float)gx[e] * (float)xv[e] * mult;
      A[e] *= a;
      Hh[e] = nx + a * Hh[e];
    }
  }
  size_t o = (size_t)bid * 1024 + h0;
#pragma unroll
  for (int e = 0; e < 8; ++e) { cA[o + e] = A[e]; cH[o + e] = Hh[e]; }
}

// ---------------- scan pass 2: carries across chunks ------------------------
__global__ void scanmid_kernel(const float* __restrict__ cA,
                               const float* __restrict__ cH,
                               float* __restrict__ carry) {
  int gidx = blockIdx.x * 256 + threadIdx.x;  // 8192 = B_*H_
  int b = gidx >> 10, h = gidx & 1023;
  float run = 0.f;
  for (int c = 0; c < NC_; ++c) {
    size_t o = ((size_t)(b * NC_ + c)) * 1024 + h;
    carry[o] = run;
    run = cH[o] + cA[o] * run;
  }
}

// ---------------- scan pass 3: h, out = h*gelu(u), hn -----------------------
__global__ __launch_bounds__(128) void scan2_kernel(
    const _Float16* __restrict__ g2, const _Float16* __restrict__ x2,
    const _Float16* __restrict__ g1, const float* __restrict__ carry,
    float* __restrict__ outO, float* __restrict__ outH,
    float* __restrict__ outHn) {
  int bid = blockIdx.x;
  int b = bid >> 7, c = bid & 127;
  int h0 = threadIdx.x * 8;
  float Hh[8];
  {
    size_t o = (size_t)bid * 1024 + h0;
#pragma unroll
    for (int e = 0; e < 8; ++e) Hh[e] = carry[o + e];
  }
  size_t mbase = (size_t)b * T_ + (size_t)c * CL_;
  for (int i = 0; i < CL_; ++i) {
    size_t m = mbase + i;
    half8 gx = *(const half8*)&g2[m * 2048 + h0];
    half8 av = *(const half8*)&g2[m * 2048 + 1024 + h0];
    half8 xv = *(const half8*)&x2[m * 1024 + h0];
    half8 uv = *(const half8*)&g1[m * 2048 + 1024 + h0];
    f32x4 hO[2], oO[2];
#pragma unroll
    for (int e = 0; e < 8; ++e) {
      float a = (float)av[e];
      float mult = sqrtf(fmaxf(1.f - a * a, 0.f));
      float nx = (float)gx[e] * (float)xv[e] * mult;
      float v = nx + a * Hh[e];
      Hh[e] = v;
      float u = (float)uv[e];
      float y = 0.5f * u * (1.f + erff(u * 0.70710678118654752f));  // exact gelu
      hO[e >> 2][e & 3] = v;
      oO[e >> 2][e & 3] = v * y;
    }
    size_t ob = m * 1024 + h0;
    *(f32x4*)&outH[ob]     = hO[0];
    *(f32x4*)&outH[ob + 4] = hO[1];
    *(f32x4*)&outO[ob]     = oO[0];
    *(f32x4*)&outO[ob + 4] = oO[1];
  }
  if (c == NC_ - 1) {
    size_t o = (size_t)b * 1024 + h0;
#pragma unroll
    for (int e = 0; e < 8; ++e) outHn[o + e] = Hh[e];
  }
}

// ---------------------------------------------------------------------------
extern "C" void kernel_launch(void* const* d_in, const int* in_sizes, int n_in,
                              void* d_out, int out_size, void* d_ws,
                              size_t ws_size, hipStream_t stream) {
  const float* x   = (const float*)d_in[0];
  const float* wx  = (const float*)d_in[1];
  const float* bx  = (const float*)d_in[2];
  const float* wy  = (const float*)d_in[3];
  const float* by  = (const float*)d_in[4];
  const float* cw  = (const float*)d_in[5];
  const float* cb  = (const float*)d_in[6];
  const float* giw = (const float*)d_in[7];
  const float* gib = (const float*)d_in[8];
  const float* gaw = (const float*)d_in[9];
  const float* gab = (const float*)d_in[10];
  const float* ap  = (const float*)d_in[11];

  char* ws = (char*)d_ws;
  size_t off = 0;
  auto alloc = [&](size_t bytes) {
    char* p = ws + off;
    off += (bytes + 255) & ~(size_t)255;
    return p;
  };
  _Float16* wT1 = (_Float16*)alloc((size_t)2048 * 1024 * 2);  // [n][k] fp16
  _Float16* wT2 = (_Float16*)alloc((size_t)2048 * 1024 * 2);
  float*    b1  = (float*)alloc(2048 * 4);
  float*    b2  = (float*)alloc(2048 * 4);
  _Float16* xh  = (_Float16*)alloc((size_t)M_ * 1024 * 2);  // x fp16; aliased
  _Float16* g2e = (_Float16*)alloc((size_t)M_ * 1024 * 2);  // extension
  (void)g2e;
  _Float16* g1o = (_Float16*)alloc((size_t)M_ * 2048 * 2);  // [x1 | u]
  _Float16* x2h = (_Float16*)alloc((size_t)M_ * 1024 * 2);  // x2
  float* cA  = (float*)alloc((size_t)B_ * NC_ * 1024 * 4);
  float* cH  = (float*)alloc((size_t)B_ * NC_ * 1024 * 4);
  float* cin = (float*)alloc((size_t)B_ * NC_ * 1024 * 4);
  _Float16* g2o = xh;  // [gx | a], 134MB spanning xh+g2e (xh dead by then)

  float* oO  = (float*)d_out;
  float* oH  = oO + (size_t)M_ * 1024;
  float* oHn = oO + (size_t)2 * M_ * 1024;

  transpose_cvt<<<dim3(64, 32), 256, 0, stream>>>(wx, wy, wT1);
  transpose_cvt<<<dim3(64, 32), 256, 0, stream>>>(giw, gaw, wT2);
  prep_bias<<<4, 1024, 0, stream>>>(bx, by, gib, gab, b1, b2);
  cvt_fp16<<<2048, 256, 0, stream>>>(x, xh, (long)M_ * 1024 / 4);

  gemm256_kernel<0><<<1024, 512, 0, stream>>>(xh, wT1, b1, nullptr, g1o);
  conv_kernel<<<16384, 256, 0, stream>>>(g1o, cw, cb, x2h);
  gemm128_kernel<1><<<4096, 256, 0, stream>>>(x2h, wT2, b2, ap, g2o);

  scan1_kernel<<<B_ * NC_, 128, 0, stream>>>(g2o, x2h, cA, cH);
  scanmid_kernel<<<32, 256, 0, stream>>>(cA, cH, cin);
  scan2_kernel<<<B_ * NC_, 128, 0, stream>>>(g2o, x2h, g1o, cin, oO, oH, oHn);
}

// Round 9
// 613.449 us; speedup vs baseline: 1.0245x; 1.0146x over previous
//
#include <hip/hip_runtime.h>
#include <math.h>

// ---------------------------------------------------------------------------
// GriffinRecurrentBlock. R9: consolidation. gemm256 (2-barrier counted
// vmcnt(8) pipeline, proven R8) in BOTH GEMM slots; scanmid unrolled x8 so
// its 128 serial HBM loads batch-issue (was 1 latency exposure per chunk).
// Tail audit: scan2/conv/scan1/cvt are at their memory rooflines.
// ---------------------------------------------------------------------------

#define B_ 8
#define T_ 4096
#define H_ 1024
#define M_ (B_ * T_)          // 32768
#define NC_ 128               // chunks per sequence
#define CL_ 32                // chunk length (T_/NC_)

typedef _Float16 half8 __attribute__((ext_vector_type(8)));
typedef _Float16 half4 __attribute__((ext_vector_type(4)));
typedef float    f32x4 __attribute__((ext_vector_type(4)));

#define SCHED0 __builtin_amdgcn_sched_barrier(0)
#define WAITBAR(N)                                                            \
  do {                                                                        \
    asm volatile("s_waitcnt vmcnt(" #N ") lgkmcnt(0)");                       \
    SCHED0;                                                                   \
    __builtin_amdgcn_s_barrier();                                             \
    SCHED0;                                                                   \
  } while (0)
#define MFMA16(a, b, c) __builtin_amdgcn_mfma_f32_16x16x32_f16((a), (b), (c), 0, 0, 0)

__device__ __forceinline__ void load16_lds(const _Float16* g, _Float16* l) {
  __builtin_amdgcn_global_load_lds(
      (const __attribute__((address_space(1))) void*)g,
      (__attribute__((address_space(3))) void*)l, 16, 0, 0);
}

// ---------------- prep: 32x32 LDS transpose + fp32->fp16 -------------------
__global__ __launch_bounds__(256) void transpose_cvt(
    const float* __restrict__ sA, const float* __restrict__ sB,
    _Float16* __restrict__ dst) {
  __shared__ float tile[32][33];
  int bn = blockIdx.x * 32;
  int bk = blockIdx.y * 32;
  const float* src = (bn < 1024) ? sA : sB;
  int nof = (bn < 1024) ? bn : bn - 1024;
  int c  = threadIdx.x & 31;
  int r0 = threadIdx.x >> 5;
#pragma unroll
  for (int i = 0; i < 4; ++i) {
    int r = r0 + i * 8;
    tile[r][c] = src[(size_t)(bk + r) * 1024 + nof + c];
  }
  __syncthreads();
#pragma unroll
  for (int i = 0; i < 4; ++i) {
    int nl = r0 + i * 8;
    dst[(size_t)(bn + nl) * 1024 + bk + c] = (_Float16)tile[c][nl];
  }
}

__global__ void prep_bias(const float* __restrict__ bx, const float* __restrict__ by,
                          const float* __restrict__ gib, const float* __restrict__ gab,
                          float* __restrict__ b1, float* __restrict__ b2) {
  int i = blockIdx.x * 1024 + threadIdx.x;   // 0..4095
  if (i < 1024)      b1[i] = bx[i];
  else if (i < 2048) b1[i] = by[i - 1024];
  else if (i < 3072) b2[i - 2048] = gib[i - 2048];
  else               b2[i - 2048] = gab[i - 3072];
}

__global__ __launch_bounds__(256) void cvt_fp16(
    const float* __restrict__ x, _Float16* __restrict__ xh, long n4) {
  for (long i = (long)blockIdx.x * 256 + threadIdx.x; i < n4;
       i += (long)gridDim.x * 256) {
    f32x4 v = ((const f32x4*)x)[i];
    half4 h;
#pragma unroll
    for (int e = 0; e < 4; ++e) h[e] = (_Float16)v[e];
    ((half4*)xh)[i] = h;
  }
}

// ================= gemm256: 2-barrier-per-K-tile counted pipeline ===========
// C[M][2048] = A[M][1024] * Bt[2048][1024]^T. 256x256 tile, 8 waves (2m x 4n),
// BK=64, 16 K-tiles. LDS: A,B each 4 units of 16KB ([256 rows][32 halfs],
// 16B-block XOR swizzle j ^= (row>>1)&3, source-pre-permuted).
// Per K-tile: p0{read kh0 a0+b, stage(t+1,k1), 16 MFMA}
//             p1{read kh0 a1, 16 MFMA} WAITBAR(8)
//             p2{read kh1 a0+b, stage(t+2,k0), 16 MFMA}
//             p3{read kh1 a1, 16 MFMA} WAITBAR(8)
template <int MODE>
__global__ __launch_bounds__(512, 2) void gemm256_kernel(
    const _Float16* __restrict__ A, const _Float16* __restrict__ Bt,
    const float* __restrict__ bias, const float* __restrict__ a_param,
    _Float16* __restrict__ C) {
  __shared__ _Float16 ldsA[32768];   // 64 KB: [slot][kh] 4 units of 8192
  __shared__ _Float16 ldsB[32768];   // 64 KB
  int tid  = threadIdx.x;
  int lane = tid & 63;
  int wave = tid >> 6;
  int l15 = lane & 15, g = lane >> 4;

  // XCD-bijective swizzle (grid = 1024 = 8*128)
  int nb = ((int)blockIdx.x & 7) * 128 + ((int)blockIdx.x >> 3);
  int m0 = (nb >> 3) * 256;           // 128 m-tiles
  int n0 = (nb & 7) * 256;            // 8 n-tiles
  int wm = wave >> 2;                 // 0..1
  int wn = wave & 3;                  // 0..3

  // ---- epilogue constants FIRST (oldest vmcnt events; prologue wait absorbs
  //      them whether or not the compiler sinks them to the epilogue).
  int   gn[4];
  float bs[4], sp[4];
#pragma unroll
  for (int nj = 0; nj < 4; ++nj) {
    gn[nj] = n0 + wn * 64 + nj * 16 + l15;
    bs[nj] = bias[gn[nj]];
    sp[nj] = 0.f;
    if (MODE == 1 && gn[nj] >= 1024)
      sp[nj] = log1pf(expf(a_param[gn[nj] - 1024]));   // softplus
  }
  SCHED0;

  // ---- staging addressing: row = tid>>2, phys 16B-block tid&3,
  //      global block = (tid&3) ^ f(row), f(row) = (row>>1)&3 = (tid>>3)&3.
  int gsrc = (tid & 3) ^ ((tid >> 3) & 3);
  const _Float16* pA = A  + (size_t)(m0 + (tid >> 2)) * 1024 + gsrc * 8;
  const _Float16* pB = Bt + (size_t)(n0 + (tid >> 2)) * 1024 + gsrc * 8;
  _Float16* stA = ldsA + wave * 512;  // HW adds lane*16B
  _Float16* stB = ldsB + wave * 512;

#define STAGE_A(kt, kh)                                                       \
  do {                                                                        \
    const _Float16* s_ = pA + (kt) * 64 + (kh) * 32;                          \
    _Float16* d_ = stA + (((kt) & 1) * 2 + (kh)) * 8192;                      \
    load16_lds(s_, d_);                    /* rows   0..127 */                \
    load16_lds(s_ + 131072, d_ + 4096);    /* rows 128..255 */                \
  } while (0)
#define STAGE_B(kt, kh)                                                       \
  do {                                                                        \
    const _Float16* s_ = pB + (kt) * 64 + (kh) * 32;                          \
    _Float16* d_ = stB + (((kt) & 1) * 2 + (kh)) * 8192;                      \
    load16_lds(s_, d_);                                                       \
    load16_lds(s_ + 131072, d_ + 4096);                                       \
  } while (0)

  // ---- fragment read offsets (halfs): row r at r*32, block j = g ^ f(r);
  //      all row offsets are 16-multiples so f(r) depends only on l15.
  int jj8  = ((g ^ ((l15 >> 1) & 3)) << 3);
  int aoff = wm * 4096 + l15 * 32 + jj8;   // + slot*16384 + kh*8192 + mi*512
  int boff = wn * 2048 + l15 * 32 + jj8;   // + slot*16384 + kh*8192 + nj*512

  f32x4 acc[8][4];
#pragma unroll
  for (int i = 0; i < 8; ++i)
#pragma unroll
    for (int j = 0; j < 4; ++j) acc[i][j] = (f32x4){0.f, 0.f, 0.f, 0.f};

  half8 a0[4], a1[4], b[4];

#define KTILE(SL, ST0, ST2, WB1, WB2)                                         \
  do {                                                                        \
    const int pl = (SL) * 16384;                                              \
    /* ---- p0: kh0, mi 0-3 (+ stage next k1) ---- */                         \
    _Pragma("unroll") for (int q = 0; q < 4; ++q)                             \
      a0[q] = *(const half8*)(ldsA + pl + q * 512 + aoff);                    \
    _Pragma("unroll") for (int q = 0; q < 4; ++q)                             \
      b[q]  = *(const half8*)(ldsB + pl + q * 512 + boff);                    \
    ST0;                                                                      \
    __builtin_amdgcn_s_setprio(1);                                            \
    _Pragma("unroll") for (int q = 0; q < 4; ++q) {                           \
      acc[q][0] = MFMA16(a0[q], b[0], acc[q][0]);                             \
      acc[q][1] = MFMA16(a0[q], b[1], acc[q][1]);                             \
      acc[q][2] = MFMA16(a0[q], b[2], acc[q][2]);                             \
      acc[q][3] = MFMA16(a0[q], b[3], acc[q][3]);                             \
    }                                                                         \
    __builtin_amdgcn_s_setprio(0);                                            \
    /* ---- p1: kh0, mi 4-7 ---- */                                           \
    _Pragma("unroll") for (int q = 0; q < 4; ++q)                             \
      a1[q] = *(const half8*)(ldsA + pl + 2048 + q * 512 + aoff);             \
    __builtin_amdgcn_s_setprio(1);                                            \
    _Pragma("unroll") for (int q = 0; q < 4; ++q) {                           \
      acc[4 + q][0] = MFMA16(a1[q], b[0], acc[4 + q][0]);                     \
      acc[4 + q][1] = MFMA16(a1[q], b[1], acc[4 + q][1]);                     \
      acc[4 + q][2] = MFMA16(a1[q], b[2], acc[4 + q][2]);                     \
      acc[4 + q][3] = MFMA16(a1[q], b[3], acc[4 + q][3]);                     \
    }                                                                         \
    __builtin_amdgcn_s_setprio(0);                                            \
    WB1;                                                                      \
    /* ---- p2: kh1, mi 0-3 (+ stage next k0) ---- */                         \
    _Pragma("unroll") for (int q = 0; q < 4; ++q)                             \
      a0[q] = *(const half8*)(ldsA + pl + 8192 + q * 512 + aoff);             \
    _Pragma("unroll") for (int q = 0; q < 4; ++q)                             \
      b[q]  = *(const half8*)(ldsB + pl + 8192 + q * 512 + boff);             \
    ST2;                                                                      \
    __builtin_amdgcn_s_setprio(1);                                            \
    _Pragma("unroll") for (int q = 0; q < 4; ++q) {                           \
      acc[q][0] = MFMA16(a0[q], b[0], acc[q][0]);                             \
      acc[q][1] = MFMA16(a0[q], b[1], acc[q][1]);                             \
      acc[q][2] = MFMA16(a0[q], b[2], acc[q][2]);                             \
      acc[q][3] = MFMA16(a0[q], b[3], acc[q][3]);                             \
    }                                                                         \
    __builtin_amdgcn_s_setprio(0);                                            \
    /* ---- p3: kh1, mi 4-7 ---- */                                           \
    _Pragma("unroll") for (int q = 0; q < 4; ++q)                             \
      a1[q] = *(const half8*)(ldsA + pl + 8192 + 2048 + q * 512 + aoff);      \
    __builtin_amdgcn_s_setprio(1);                                            \
    _Pragma("unroll") for (int q = 0; q < 4; ++q) {                           \
      acc[4 + q][0] = MFMA16(a1[q], b[0], acc[4 + q][0]);                     \
      acc[4 + q][1] = MFMA16(a1[q], b[1], acc[4 + q][1]);                     \
      acc[4 + q][2] = MFMA16(a1[q], b[2], acc[4 + q][2]);                     \
      acc[4 + q][3] = MFMA16(a1[q], b[3], acc[4 + q][3]);                     \
    }                                                                         \
    __builtin_amdgcn_s_setprio(0);                                            \
    WB2;                                                                      \
  } while (0)

  // prologue: tile0 kh0/kh1 + tile1 kh0 in flight; WAITBAR(8) completes the
  // pre-loads + tile0 kh0 (and p1's WAITBAR(8) completes tile0 kh1).
  STAGE_A(0, 0); STAGE_B(0, 0);
  STAGE_A(0, 1); STAGE_B(0, 1);
  STAGE_A(1, 0); STAGE_B(1, 0);
  WAITBAR(8);

  for (int t = 0; t < 14; ++t) {
    KTILE((t & 1),
          { STAGE_A(t + 1, 1); STAGE_B(t + 1, 1); },
          { STAGE_A(t + 2, 0); STAGE_B(t + 2, 0); },
          WAITBAR(8), WAITBAR(8));
  }
  // t = 14: no (t+2) tile; second wait shrinks to vmcnt(4).
  KTILE(0, { STAGE_A(15, 1); STAGE_B(15, 1); }, (void)0, WAITBAR(8), WAITBAR(4));
  // t = 15: nothing to stage; first wait drains the last k1 units.
  KTILE(1, (void)0, (void)0, WAITBAR(0), (void)0);

  // epilogue: C/D layout col=lane&15, row=(lane>>4)*4+p
#pragma unroll
  for (int mi = 0; mi < 8; ++mi) {
#pragma unroll
    for (int p = 0; p < 4; ++p) {
      int gm = m0 + wm * 128 + mi * 16 + g * 4 + p;
      size_t rowb = (size_t)gm * 2048;
#pragma unroll
      for (int nj = 0; nj < 4; ++nj) {
        float v = acc[mi][nj][p] + bs[nj];
        if (MODE == 1) {
          float s = 1.f / (1.f + expf(-v));
          if (gn[nj] < 1024) {
            v = s;                          // gate_x
          } else {
            float av = expf(-8.f * s * sp[nj]);
            if ((gm & (T_ - 1)) == 0) av = 0.f;   // t == 0
            v = av;
          }
        }
        C[rowb + gn[nj]] = (_Float16)v;
      }
    }
  }
#undef STAGE_A
#undef STAGE_B
#undef KTILE
}

// ---------------- conv: x2 = sum_j cw[3-j]*x1[t-j] + cb ---------------------
__global__ __launch_bounds__(256) void conv_kernel(
    const _Float16* __restrict__ g1, const float* __restrict__ cw,
    const float* __restrict__ cb, _Float16* __restrict__ x2) {
  int idx = blockIdx.x * 256 + threadIdx.x;   // over M_*H_/8
  int m  = idx >> 7;
  int hb = (idx & 127) * 8;
  int t  = m & (T_ - 1);
  float acc[8];
#pragma unroll
  for (int e = 0; e < 8; ++e) acc[e] = cb[hb + e];
#pragma unroll
  for (int j = 0; j < 4; ++j) {
    if (t >= j) {
      half8 xv = *(const half8*)&g1[(size_t)(m - j) * 2048 + hb];
      const float* w = &cw[(3 - j) * 1024 + hb];
#pragma unroll
      for (int e = 0; e < 8; ++e) acc[e] += w[e] * (float)xv[e];
    }
  }
  half8 o;
#pragma unroll
  for (int e = 0; e < 8; ++e) o[e] = (_Float16)acc[e];
  *(half8*)&x2[(size_t)m * 1024 + hb] = o;
}

// ---------------- scan pass 1: per-chunk (prod a, local h) ------------------
__global__ __launch_bounds__(128) void scan1_kernel(
    const _Float16* __restrict__ g2, const _Float16* __restrict__ x2,
    float* __restrict__ cA, float* __restrict__ cH) {
  int bid = blockIdx.x;          // b*NC_ + c
  int b = bid >> 7, c = bid & 127;
  int h0 = threadIdx.x * 8;
  float A[8], Hh[8];
#pragma unroll
  for (int e = 0; e < 8; ++e) { A[e] = 1.f; Hh[e] = 0.f; }
  size_t mbase = (size_t)b * T_ + (size_t)c * CL_;
  for (int i = 0; i < CL_; ++i) {
    size_t m = mbase + i;
    half8 gx = *(const half8*)&g2[m * 2048 + h0];
    half8 av = *(const half8*)&g2[m * 2048 + 1024 + h0];
    half8 xv = *(const half8*)&x2[m * 1024 + h0];
#pragma unroll
    for (int e = 0; e < 8; ++e) {
      float a = (float)av[e];
      float mult = sqrtf(fmaxf(1.f - a * a, 0.f));
      float nx = (float)gx[e] * (float)xv[e] * mult;
      A[e] *= a;
      Hh[e] = nx + a * Hh[e];
    }
  }
  size_t o = (size_t)bid * 1024 + h0;
#pragma unroll
  for (int e = 0; e < 8; ++e) { cA[o + e] = A[e]; cH[o + e] = Hh[e]; }
}

// ---------------- scan pass 2: carries across chunks ------------------------
// Serial over 128 chunks but loads are address-independent: unroll x8 so the
// HBM latency is paid once per 8 chunks, not per chunk.
__global__ void scanmid_kernel(const float* __restrict__ cA,
                               const float* __restrict__ cH,
                               float* __restrict__ carry) {
  int gidx = blockIdx.x * 256 + threadIdx.x;  // 8192 = B_*H_
  int b = gidx >> 10, h = gidx & 1023;
  const float* pa = cA + (size_t)b * NC_ * 1024 + h;
  const float* ph = cH + (size_t)b * NC_ * 1024 + h;
  float* pc = carry + (size_t)b * NC_ * 1024 + h;
  float run = 0.f;
  for (int c0 = 0; c0 < NC_; c0 += 8) {
    float av[8], hv[8];
#pragma unroll
    for (int k = 0; k < 8; ++k) {
      av[k] = pa[(size_t)(c0 + k) * 1024];
      hv[k] = ph[(size_t)(c0 + k) * 1024];
    }
#pragma unroll
    for (int k = 0; k < 8; ++k) {
      pc[(size_t)(c0 + k) * 1024] = run;
      run = hv[k] + av[k] * run;
    }
  }
}

// ---------------- scan pass 3: h, out = h*gelu(u), hn -----------------------
__global__ __launch_bounds__(128) void scan2_kernel(
    const _Float16* __restrict__ g2, const _Float16* __restrict__ x2,
    const _Float16* __restrict__ g1, const float* __restrict__ carry,
    float* __restrict__ outO, float* __restrict__ outH,
    float* __restrict__ outHn) {
  int bid = blockIdx.x;
  int b = bid >> 7, c = bid & 127;
  int h0 = threadIdx.x * 8;
  float Hh[8];
  {
    size_t o = (size_t)bid * 1024 + h0;
#pragma unroll
    for (int e = 0; e < 8; ++e) Hh[e] = carry[o + e];
  }
  size_t mbase = (size_t)b * T_ + (size_t)c * CL_;
  for (int i = 0; i < CL_; ++i) {
    size_t m = mbase + i;
    half8 gx = *(const half8*)&g2[m * 2048 + h0];
    half8 av = *(const half8*)&g2[m * 2048 + 1024 + h0];
    half8 xv = *(const half8*)&x2[m * 1024 + h0];
    half8 uv = *(const half8*)&g1[m * 2048 + 1024 + h0];
    f32x4 hO[2], oO[2];
#pragma unroll
    for (int e = 0; e < 8; ++e) {
      float a = (float)av[e];
      float mult = sqrtf(fmaxf(1.f - a * a, 0.f));
      float nx = (float)gx[e] * (float)xv[e] * mult;
      float v = nx + a * Hh[e];
      Hh[e] = v;
      float u = (float)uv[e];
      float y = 0.5f * u * (1.f + erff(u * 0.70710678118654752f));  // exact gelu
      hO[e >> 2][e & 3] = v;
      oO[e >> 2][e & 3] = v * y;
    }
    size_t ob = m * 1024 + h0;
    *(f32x4*)&outH[ob]     = hO[0];
    *(f32x4*)&outH[ob + 4] = hO[1];
    *(f32x4*)&outO[ob]     = oO[0];
    *(f32x4*)&outO[ob + 4] = oO[1];
  }
  if (c == NC_ - 1) {
    size_t o = (size_t)b * 1024 + h0;
#pragma unroll
    for (int e = 0; e < 8; ++e) outHn[o + e] = Hh[e];
  }
}

// ---------------------------------------------------------------------------
extern "C" void kernel_launch(void* const* d_in, const int* in_sizes, int n_in,
                              void* d_out, int out_size, void* d_ws,
                              size_t ws_size, hipStream_t stream) {
  const float* x   = (const float*)d_in[0];
  const float* wx  = (const float*)d_in[1];
  const float* bx  = (const float*)d_in[2];
  const float* wy  = (const float*)d_in[3];
  const float* by  = (const float*)d_in[4];
  const float* cw  = (const float*)d_in[5];
  const float* cb  = (const float*)d_in[6];
  const float* giw = (const float*)d_in[7];
  const float* gib = (const float*)d_in[8];
  const float* gaw = (const float*)d_in[9];
  const float* gab = (const float*)d_in[10];
  const float* ap  = (const float*)d_in[11];

  char* ws = (char*)d_ws;
  size_t off = 0;
  auto alloc = [&](size_t bytes) {
    char* p = ws + off;
    off += (bytes + 255) & ~(size_t)255;
    return p;
  };
  _Float16* wT1 = (_Float16*)alloc((size_t)2048 * 1024 * 2);  // [n][k] fp16
  _Float16* wT2 = (_Float16*)alloc((size_t)2048 * 1024 * 2);
  float*    b1  = (float*)alloc(2048 * 4);
  float*    b2  = (float*)alloc(2048 * 4);
  _Float16* xh  = (_Float16*)alloc((size_t)M_ * 1024 * 2);  // x fp16; aliased
  _Float16* g2e = (_Float16*)alloc((size_t)M_ * 1024 * 2);  // extension
  (void)g2e;
  _Float16* g1o = (_Float16*)alloc((size_t)M_ * 2048 * 2);  // [x1 | u]
  _Float16* x2h = (_Float16*)alloc((size_t)M_ * 1024 * 2);  // x2
  float* cA  = (float*)alloc((size_t)B_ * NC_ * 1024 * 4);
  float* cH  = (float*)alloc((size_t)B_ * NC_ * 1024 * 4);
  float* cin = (float*)alloc((size_t)B_ * NC_ * 1024 * 4);
  _Float16* g2o = xh;  // [gx | a], 134MB spanning xh+g2e (xh dead by then)

  float* oO  = (float*)d_out;
  float* oH  = oO + (size_t)M_ * 1024;
  float* oHn = oO + (size_t)2 * M_ * 1024;

  transpose_cvt<<<dim3(64, 32), 256, 0, stream>>>(wx, wy, wT1);
  transpose_cvt<<<dim3(64, 32), 256, 0, stream>>>(giw, gaw, wT2);
  prep_bias<<<4, 1024, 0, stream>>>(bx, by, gib, gab, b1, b2);
  cvt_fp16<<<2048, 256, 0, stream>>>(x, xh, (long)M_ * 1024 / 4);

  gemm256_kernel<0><<<1024, 512, 0, stream>>>(xh, wT1, b1, nullptr, g1o);
  conv_kernel<<<16384, 256, 0, stream>>>(g1o, cw, cb, x2h);
  gemm256_kernel<1><<<1024, 512, 0, stream>>>(x2h, wT2, b2, ap, g2o);

  scan1_kernel<<<B_ * NC_, 128, 0, stream>>>(g2o, x2h, cA, cH);
  scanmid_kernel<<<32, 256, 0, stream>>>(cA, cH, cin);
  scan2_kernel<<<B_ * NC_, 128, 0, stream>>>(g2o, x2h, g1o, cin, oO, oH, oHn);
}